// Round 1
// baseline (4386.848 us; speedup 1.0000x reference)
//
#include <hip/hip_runtime.h>

#define LRELU 0.2f
#define EPS_D 1e-8f

static constexpr int B = 8;
static constexpr int C = 512;          // Cin = Cout = S = 512
static constexpr int HO = 64, WO = 64; // output spatial
static constexpr int HW = HO * WO;     // 4096
static constexpr int HIN = 32;

// workspace layout (in floats)
static constexpr size_t XSUP_OFF = 0;                          // B*C*HW
static constexpr size_t H1_OFF   = (size_t)B * C * HW;         // B*C*HW
static constexpr size_t S1_OFF   = 2 * (size_t)B * C * HW;
static constexpr size_t S2_OFF   = S1_OFF + (size_t)B * C;
static constexpr size_t SR_OFF   = S2_OFF + (size_t)B * C;
static constexpr size_t D1_OFF   = SR_OFF + (size_t)B * C;
static constexpr size_t D2_OFF   = D1_OFF + (size_t)B * C;

// ---------------------------------------------------------------------------
// styles: s[b][i] = mod_b[i] + sum_j w[b][j] * mod_w[i][j]
// grid = B blocks, 256 threads
__global__ void k_styles(const float* __restrict__ wsty,
                         const float* __restrict__ mw,
                         const float* __restrict__ mb,
                         float* __restrict__ sout) {
  __shared__ float wsh[C];
  int b = blockIdx.x;
  int t = threadIdx.x;
  wsh[t]       = wsty[b * C + t];
  wsh[t + 256] = wsty[b * C + t + 256];
  __syncthreads();
  for (int i = t; i < C; i += 256) {
    float acc = mb[i];
    const float* row = mw + (size_t)i * C;
#pragma unroll 4
    for (int j = 0; j < C; ++j) acc = fmaf(wsh[j], row[j], acc);
    sout[b * C + i] = acc;
  }
}

// ---------------------------------------------------------------------------
// demod: d[b][co] = rsqrt( sum_ci s[b][ci]^2 * sum_tap W[co][ci][tap]^2 + eps )
// grid = C blocks (one per co), 256 threads
__global__ void k_demod(const float* __restrict__ Wgt,  // [C][C][9]
                        const float* __restrict__ s,    // [B][C]
                        float* __restrict__ dout) {     // [B][C]
  __shared__ float ssq[B * C];
  __shared__ float red[4][B];
  int co = blockIdx.x;
  int t = threadIdx.x;
  for (int idx = t; idx < B * C; idx += 256) {
    float v = s[idx];
    ssq[idx] = v * v;
  }
  __syncthreads();
  float p[B];
#pragma unroll
  for (int b = 0; b < B; ++b) p[b] = 0.f;
  int ci0 = t * 2;
#pragma unroll
  for (int k = 0; k < 2; ++k) {
    int ci = ci0 + k;
    const float* wp = Wgt + (size_t)co * C * 9 + (size_t)ci * 9;
    float wsq = 0.f;
#pragma unroll
    for (int tp = 0; tp < 9; ++tp) wsq = fmaf(wp[tp], wp[tp], wsq);
#pragma unroll
    for (int b = 0; b < B; ++b) p[b] = fmaf(ssq[b * C + ci], wsq, p[b]);
  }
  int lane = t & 63, wv = t >> 6;
#pragma unroll
  for (int b = 0; b < B; ++b) {
    float v = p[b];
    for (int off = 32; off; off >>= 1) v += __shfl_down(v, off);
    if (lane == 0) red[wv][b] = v;
  }
  __syncthreads();
  if (t < B) {
    float tot = red[0][t] + red[1][t] + red[2][t] + red[3][t];
    dout[t * C + co] = rsqrtf(tot + EPS_D);
  }
}

// ---------------------------------------------------------------------------
// bilinear 2x upsample (align_corners=False / half-pixel), fused with style s1.
// out[o] maps to src coord o/2 - 0.25; taps clamped at borders.
__device__ __forceinline__ void up1d(int o, int& i0, int& i1, float& w0, float& w1) {
  float src = 0.5f * (float)o - 0.25f;
  float f = floorf(src);
  float fr = src - f;
  int i = (int)f;
  i0 = i < 0 ? 0 : i;
  int j = i + 1;
  i1 = j > (HIN - 1) ? (HIN - 1) : j;
  w1 = fr;
  w0 = 1.0f - fr;
}

// grid = B*C blocks, 256 threads
__global__ void k_upsample(const float* __restrict__ x,   // [B][C][32][32]
                           const float* __restrict__ s1,  // [B][C]
                           float* __restrict__ xsup) {    // [B][C][64][64]
  __shared__ float xt[HIN * HIN];
  int bx = blockIdx.x;
  int b = bx >> 9, ci = bx & 511;
  int t = threadIdx.x;
  const float* src = x + ((size_t)b * C + ci) * (HIN * HIN);
#pragma unroll
  for (int k = 0; k < 4; ++k) xt[t + 256 * k] = src[t + 256 * k];
  __syncthreads();
  float s = s1[b * C + ci];
  float* dst = xsup + ((size_t)b * C + ci) * HW;
  for (int k = 0; k < 16; ++k) {
    int p = t + 256 * k;
    int yo = p >> 6, xo = p & 63;
    int y0, y1, x0i, x1i;
    float wy0, wy1, wx0, wx1;
    up1d(yo, y0, y1, wy0, wy1);
    up1d(xo, x0i, x1i, wx0, wx1);
    float v = wy0 * (wx0 * xt[y0 * HIN + x0i] + wx1 * xt[y0 * HIN + x1i]) +
              wy1 * (wx0 * xt[y1 * HIN + x0i] + wx1 * xt[y1 * HIN + x1i]);
    dst[p] = s * v;
  }
}

// ---------------------------------------------------------------------------
// Tiled fp32 3x3 conv, 512->512, 64x64 spatial, pad 1.
// Block: 64 Cout x (4 rows x 64 cols). Thread: 8 co x 8 px register tile.
// K-loop over Cin in chunks of 8 staged in LDS (input with halo + weights).
// Epilogue: out = leaky(acc * d[b][co] + nscale[co] * noise[b][y][x])
// grid = B * 8 * 16 = 1024 blocks, 256 threads
template <bool SCALE_IN>
__global__ __launch_bounds__(256) void k_conv3x3(
    const float* __restrict__ in,      // [B][C][64][64]
    const float* __restrict__ Wgt,     // [C][C][9]
    const float* __restrict__ sin_,    // [B][C] or unused
    const float* __restrict__ dmod,    // [B][C]
    const float* __restrict__ nscale,  // [C]
    const float* __restrict__ noise,   // [B][HW]
    float* __restrict__ out) {         // [B][C][64][64]
  __shared__ float xs[8 * 6 * 66];  // [ci][row 0..5][col 0..65], halo of 1
  __shared__ float wsm[64 * 72];    // [co][ci*9+tap]

  int bx = blockIdx.x;
  int b = bx >> 7;
  int rem = bx & 127;
  int cot = rem >> 4;
  int rt = rem & 15;
  int y0 = rt * 4;
  int co_base = cot * 64;
  int t = threadIdx.x;
  int tco = t >> 5;   // 0..7
  int tpx = t & 31;   // 0..31

  float acc[8][8];
#pragma unroll
  for (int u = 0; u < 8; ++u)
#pragma unroll
    for (int v = 0; v < 8; ++v) acc[u][v] = 0.f;

  for (int ck = 0; ck < C / 8; ++ck) {
    int cib = ck * 8;
    __syncthreads();
    // stage input tile with halo (zero-padded), optional per-ci style scale
    for (int idx = t; idx < 8 * 6 * 66; idx += 256) {
      int ci = idx / 396;
      int r2 = idx - ci * 396;
      int r = r2 / 66;
      int c = r2 - r * 66;
      int gy = y0 + r - 1;
      int gx = c - 1;
      float v = 0.f;
      if ((unsigned)gy < 64u && (unsigned)gx < 64u) {
        v = in[(((size_t)b * C + cib + ci) * 64 + gy) * 64 + gx];
        if (SCALE_IN) v *= sin_[b * C + cib + ci];
      }
      xs[idx] = v;
    }
    // stage weights: per co, the 8ci x 9tap = 72 floats are contiguous in src
    const float* wsrc = Wgt + (size_t)co_base * (C * 9) + (size_t)cib * 9;
    for (int idx = t; idx < 64 * 72; idx += 256) {
      int co = idx / 72;
      int r = idx - co * 72;
      wsm[idx] = wsrc[(size_t)co * (C * 9) + r];
    }
    __syncthreads();

#pragma unroll 1
    for (int ci = 0; ci < 8; ++ci) {
      const float* wrow = &wsm[(tco * 8) * 72 + ci * 9];
      const float* xbase = &xs[ci * 396 + tpx];
#pragma unroll
      for (int dy = 0; dy < 3; ++dy) {
#pragma unroll
        for (int dx = 0; dx < 3; ++dx) {
          int tap = dy * 3 + dx;
          float wv[8], xv[8];
#pragma unroll
          for (int u = 0; u < 8; ++u) wv[u] = wrow[u * 72 + tap];
#pragma unroll
          for (int v = 0; v < 8; ++v)
            xv[v] = xbase[(dy + (v >> 1)) * 66 + dx + ((v & 1) << 5)];
#pragma unroll
          for (int u = 0; u < 8; ++u)
#pragma unroll
            for (int v = 0; v < 8; ++v)
              acc[u][v] = fmaf(wv[u], xv[v], acc[u][v]);
        }
      }
    }
  }

  // epilogue: demod, noise, leaky
  float dreg[8], nsr[8], nz[8];
#pragma unroll
  for (int u = 0; u < 8; ++u) {
    int co = co_base + tco * 8 + u;
    dreg[u] = dmod[b * C + co];
    nsr[u] = nscale[co];
  }
#pragma unroll
  for (int v = 0; v < 8; ++v)
    nz[v] = noise[b * HW + (y0 + (v >> 1)) * 64 + tpx + ((v & 1) << 5)];
#pragma unroll
  for (int u = 0; u < 8; ++u) {
    int co = co_base + tco * 8 + u;
#pragma unroll
    for (int v = 0; v < 8; ++v) {
      float val = fmaf(acc[u][v], dreg[u], nsr[u] * nz[v]);
      val = val >= 0.f ? val : LRELU * val;
      out[(((size_t)b * C + co) * 64 + y0 + (v >> 1)) * 64 + tpx + ((v & 1) << 5)] = val;
    }
  }
}

// ---------------------------------------------------------------------------
// 1x1 toRGB (no demod, no noise, no activation):
// rgb[b][c][p] = sum_co (rgbW[c][co] * sr[b][co]) * h[b][co][p]
// grid = B*32 blocks, 128 threads (128 px per block)
__global__ void k_rgb(const float* __restrict__ h,    // [B][C][HW]
                      const float* __restrict__ rw,   // [3][C]
                      const float* __restrict__ sr,   // [B][C]
                      float* __restrict__ rgb) {      // [B][3][HW]
  __shared__ float wsr[3][C];
  int bx = blockIdx.x;
  int b = bx >> 5;
  int chunk = bx & 31;
  int t = threadIdx.x;
  for (int idx = t; idx < 3 * C; idx += 128) {
    int c = idx >> 9, co = idx & 511;
    wsr[c][co] = rw[c * C + co] * sr[b * C + co];
  }
  __syncthreads();
  int px = chunk * 128 + t;
  float a0 = 0.f, a1 = 0.f, a2 = 0.f;
  const float* hp = h + (size_t)b * C * HW + px;
#pragma unroll 4
  for (int co = 0; co < C; ++co) {
    float hv = hp[(size_t)co * HW];
    a0 = fmaf(wsr[0][co], hv, a0);
    a1 = fmaf(wsr[1][co], hv, a1);
    a2 = fmaf(wsr[2][co], hv, a2);
  }
  float* rp = rgb + (size_t)b * 3 * HW + px;
  rp[0] = a0;
  rp[HW] = a1;
  rp[2 * HW] = a2;
}

// ---------------------------------------------------------------------------
extern "C" void kernel_launch(void* const* d_in, const int* in_sizes, int n_in,
                              void* d_out, int out_size, void* d_ws, size_t ws_size,
                              hipStream_t stream) {
  (void)in_sizes; (void)n_in; (void)out_size; (void)ws_size;
  const float* x   = (const float*)d_in[0];
  const float* wst = (const float*)d_in[1];
  const float* w1  = (const float*)d_in[2];
  const float* m1w = (const float*)d_in[3];
  const float* m1b = (const float*)d_in[4];
  const float* ns1 = (const float*)d_in[5];
  const float* w2  = (const float*)d_in[6];
  const float* m2w = (const float*)d_in[7];
  const float* m2b = (const float*)d_in[8];
  const float* ns2 = (const float*)d_in[9];
  const float* rw  = (const float*)d_in[10];
  const float* mrw = (const float*)d_in[11];
  const float* mrb = (const float*)d_in[12];
  const float* nz1 = (const float*)d_in[13];
  const float* nz2 = (const float*)d_in[14];

  float* ws   = (float*)d_ws;
  float* xsup = ws + XSUP_OFF;
  float* h1   = ws + H1_OFF;
  float* s1   = ws + S1_OFF;
  float* s2   = ws + S2_OFF;
  float* srr  = ws + SR_OFF;
  float* dm1  = ws + D1_OFF;
  float* dm2  = ws + D2_OFF;

  float* hout   = (float*)d_out;                  // [B][C][HW]
  float* rgbout = hout + (size_t)B * C * HW;      // [B][3][HW]

  k_styles<<<B, 256, 0, stream>>>(wst, m1w, m1b, s1);
  k_styles<<<B, 256, 0, stream>>>(wst, m2w, m2b, s2);
  k_styles<<<B, 256, 0, stream>>>(wst, mrw, mrb, srr);
  k_demod<<<C, 256, 0, stream>>>(w1, s1, dm1);
  k_demod<<<C, 256, 0, stream>>>(w2, s2, dm2);
  k_upsample<<<B * C, 256, 0, stream>>>(x, s1, xsup);
  k_conv3x3<false><<<B * 8 * 16, 256, 0, stream>>>(xsup, w1, nullptr, dm1, ns1, nz1, h1);
  k_conv3x3<true><<<B * 8 * 16, 256, 0, stream>>>(h1, w2, s2, dm2, ns2, nz2, hout);
  k_rgb<<<B * 32, 128, 0, stream>>>(hout, rw, srr, rgbout);
}

// Round 2
// 621.828 us; speedup vs baseline: 7.0548x; 7.0548x over previous
//
#include <hip/hip_runtime.h>

#define LRELU 0.2f
#define EPS_D 1e-8f

static constexpr int B = 8;
static constexpr int C = 512;
static constexpr int HO = 64, WO = 64;
static constexpr int HW = HO * WO;     // 4096
static constexpr int HIN = 32;

typedef _Float16 f16;
typedef _Float16 f16x8 __attribute__((ext_vector_type(8)));
typedef _Float16 f16x4 __attribute__((ext_vector_type(4)));
typedef float f32x4 __attribute__((ext_vector_type(4)));

// workspace byte offsets
static constexpr size_t XUP_B = 0;                         // [B][64][64][512] f16
static constexpr size_t H1S_B = 33554432;                  // [B][64][64][512] f16
static constexpr size_t WP1_B = 67108864;                  // [9][512][512] f16
static constexpr size_t WP2_B = 71827456;                  // [9][512][512] f16
static constexpr size_t S1_B  = 76546048;                  // [B][C] f32
static constexpr size_t S2_B  = S1_B + 16384;
static constexpr size_t SR_B  = S2_B + 16384;
static constexpr size_t D1_B  = SR_B + 16384;
static constexpr size_t D2_B  = D1_B + 16384;

// ---------------------------------------------------------------------------
// styles: s[b][i] = mod_b[i] + sum_j w[b][j] * mod_w[i][j]
__global__ void k_styles(const float* __restrict__ wsty,
                         const float* __restrict__ mw,
                         const float* __restrict__ mb,
                         float* __restrict__ sout) {
  __shared__ float wsh[C];
  int b = blockIdx.x;
  int t = threadIdx.x;
  wsh[t]       = wsty[b * C + t];
  wsh[t + 256] = wsty[b * C + t + 256];
  __syncthreads();
  for (int i = t; i < C; i += 256) {
    float acc = mb[i];
    const float* row = mw + (size_t)i * C;
#pragma unroll 4
    for (int j = 0; j < C; ++j) acc = fmaf(wsh[j], row[j], acc);
    sout[b * C + i] = acc;
  }
}

// ---------------------------------------------------------------------------
// demod: d[b][co] = rsqrt( sum_ci s[b][ci]^2 * sum_tap W[co][ci][tap]^2 + eps )
__global__ void k_demod(const float* __restrict__ Wgt,  // [C][C][9] fp32
                        const float* __restrict__ s,    // [B][C]
                        float* __restrict__ dout) {     // [B][C]
  __shared__ float ssq[B * C];
  __shared__ float red[4][B];
  int co = blockIdx.x;
  int t = threadIdx.x;
  for (int idx = t; idx < B * C; idx += 256) {
    float v = s[idx];
    ssq[idx] = v * v;
  }
  __syncthreads();
  float p[B];
#pragma unroll
  for (int b = 0; b < B; ++b) p[b] = 0.f;
  int ci0 = t * 2;
#pragma unroll
  for (int k = 0; k < 2; ++k) {
    int ci = ci0 + k;
    const float* wp = Wgt + (size_t)co * C * 9 + (size_t)ci * 9;
    float wsq = 0.f;
#pragma unroll
    for (int tp = 0; tp < 9; ++tp) wsq = fmaf(wp[tp], wp[tp], wsq);
#pragma unroll
    for (int b = 0; b < B; ++b) p[b] = fmaf(ssq[b * C + ci], wsq, p[b]);
  }
  int lane = t & 63, wv = t >> 6;
#pragma unroll
  for (int b = 0; b < B; ++b) {
    float v = p[b];
    for (int off = 32; off; off >>= 1) v += __shfl_down(v, off);
    if (lane == 0) red[wv][b] = v;
  }
  __syncthreads();
  if (t < B) {
    float tot = red[0][t] + red[1][t] + red[2][t] + red[3][t];
    dout[t * C + co] = rsqrtf(tot + EPS_D);
  }
}

// ---------------------------------------------------------------------------
// weight prepack: W fp32 [co][ci][9] -> Wp f16 [tap][co][ci]
__global__ void k_packw(const float* __restrict__ w, f16* __restrict__ wp) {
  int idx = blockIdx.x * 256 + threadIdx.x;   // co*512+ci
  const float* src = w + (size_t)idx * 9;
#pragma unroll
  for (int tap = 0; tap < 9; ++tap)
    wp[(size_t)tap * (C * C) + idx] = (f16)src[tap];
}

// ---------------------------------------------------------------------------
__device__ __forceinline__ void up1d(int o, int& i0, int& i1, float& w0, float& w1) {
  float src = 0.5f * (float)o - 0.25f;
  float f = floorf(src);
  float fr = src - f;
  int i = (int)f;
  i0 = i < 0 ? 0 : i;
  int j = i + 1;
  i1 = j > (HIN - 1) ? (HIN - 1) : j;
  w1 = fr;
  w0 = 1.0f - fr;
}

// bilinear 2x upsample + s1 scale, NCHW fp32 -> NHWC f16.
// grid = B * 16 (ci chunks of 32), 256 threads
__global__ __launch_bounds__(256) void k_up(const float* __restrict__ x,
                                            const float* __restrict__ s1,
                                            f16* __restrict__ xup) {
  __shared__ f16 xt[32 * 32 * 32];  // [(y*32+x)*32 + ci]  64KB
  int bx = blockIdx.x;
  int b = bx >> 4;
  int ci0 = (bx & 15) * 32;
  int t = threadIdx.x;
  int xi_ = t & 31, cl = t >> 5;  // cl 0..7
  for (int y = 0; y < 32; ++y) {
#pragma unroll
    for (int p = 0; p < 4; ++p) {
      int ci = p * 8 + cl;
      float v = x[(((size_t)b * C + ci0 + ci) * 32 + y) * 32 + xi_];
      xt[(y * 32 + xi_) * 32 + ci] = (f16)v;
    }
  }
  __syncthreads();
  int xo = t >> 2;          // 0..63
  int cg = (t & 3) * 8;     // ci sub-base
  float sv[8];
#pragma unroll
  for (int e = 0; e < 8; ++e) sv[e] = s1[b * C + ci0 + cg + e];
  int x0, x1; float wx0, wx1;
  up1d(xo, x0, x1, wx0, wx1);
  for (int yo = 0; yo < 64; ++yo) {
    int y0, y1; float wy0, wy1;
    up1d(yo, y0, y1, wy0, wy1);
    f16x8 t00 = *(const f16x8*)&xt[(y0 * 32 + x0) * 32 + cg];
    f16x8 t01 = *(const f16x8*)&xt[(y0 * 32 + x1) * 32 + cg];
    f16x8 t10 = *(const f16x8*)&xt[(y1 * 32 + x0) * 32 + cg];
    f16x8 t11 = *(const f16x8*)&xt[(y1 * 32 + x1) * 32 + cg];
    f16x8 o;
#pragma unroll
    for (int e = 0; e < 8; ++e) {
      float v = wy0 * (wx0 * (float)t00[e] + wx1 * (float)t01[e]) +
                wy1 * (wx0 * (float)t10[e] + wx1 * (float)t11[e]);
      o[e] = (f16)(v * sv[e]);
    }
    *(f16x8*)&xup[(((size_t)b * 64 + yo) * 64 + xo) * C + ci0 + cg] = o;
  }
}

// ---------------------------------------------------------------------------
// MFMA implicit-GEMM 3x3 conv. Input NHWC f16 (style pre-applied), weights
// [tap][co][ci] f16. Block: 64 co x 256 px (4 rows x 64 cols), 4 waves, each
// wave 64co x 64px = 4x4 fragments of 16x16. K-chunk = 32 ci.
// Epilogue: v = leaky(acc*d[co] + ns[co]*noise) ; conv1: write (v*s2) NHWC f16
//           conv2: write v NCHW fp32.
__global__ __launch_bounds__(256, 2) void k_conv_mfma(
    const f16* __restrict__ xin,      // [B][64][64][C]
    const f16* __restrict__ Wp,       // [9][C][C]
    const float* __restrict__ dmod,   // [B][C]
    const float* __restrict__ nscale, // [C]
    const float* __restrict__ noise,  // [B][HW]
    const float* __restrict__ s2v,    // [B][C] (conv1 only)
    f16* __restrict__ out_nhwc,       // conv1 out or null
    float* __restrict__ out_nchw) {   // conv2 out or null
  __shared__ f16 xs[6 * 66 * 32];     // [(row*66+col)*32+ci] 25344B
  __shared__ f16 wsm[9 * 64 * 32];    // [((tap*64+co)*32)+ci] 36864B

  int bx = blockIdx.x;
  int b = bx >> 7;
  int rem = bx & 127;
  int co_base = (rem >> 4) * 64;
  int y0 = (rem & 15) * 4;
  int t = threadIdx.x;
  int lane = t & 63, wid = t >> 6;
  int ln = lane & 15, kg = lane >> 4;

  f32x4 acc[4][4] = {};

  for (int ck = 0; ck < 16; ++ck) {
    __syncthreads();
    // stage input tile with halo: 6 rows x 66 cols x 32 ci, zero-padded OOB
    for (int idx = t; idx < 1584; idx += 256) {
      int ci8 = idx & 3;
      int pc = idx >> 2;             // 0..395
      int row = pc / 66, col = pc - row * 66;
      int gy = y0 + row - 1, gx = col - 1;
      f16x8 v = {};
      if ((unsigned)gy < 64u && (unsigned)gx < 64u)
        v = *(const f16x8*)&xin[(((size_t)b * 64 + gy) * 64 + gx) * C + ck * 32 + ci8 * 8];
      *(f16x8*)&xs[pc * 32 + ci8 * 8] = v;
    }
    // stage weights: 9 taps x 64 co x 32 ci
    for (int i = 0; i < 9; ++i) {
      int idx = i * 256 + t;
      int ci8 = idx & 3;
      int co = (idx >> 2) & 63;
      int tap = idx >> 8;
      *(f16x8*)&wsm[(tap * 64 + co) * 32 + ci8 * 8] =
          *(const f16x8*)&Wp[((size_t)tap * C + co_base + co) * C + ck * 32 + ci8 * 8];
    }
    __syncthreads();

#pragma unroll
    for (int tap = 0; tap < 9; ++tap) {
      const int dy = tap / 3, dx = tap % 3;
      f16x8 af[4], bf[4];
#pragma unroll
      for (int m = 0; m < 4; ++m)
        af[m] = *(const f16x8*)&wsm[(tap * 64 + m * 16 + ln) * 32 + kg * 8];
#pragma unroll
      for (int n = 0; n < 4; ++n)
        bf[n] = *(const f16x8*)&xs[((wid + dy) * 66 + n * 16 + ln + dx) * 32 + kg * 8];
#pragma unroll
      for (int m = 0; m < 4; ++m)
#pragma unroll
        for (int n = 0; n < 4; ++n)
          acc[m][n] = __builtin_amdgcn_mfma_f32_16x16x32_f16(af[m], bf[n], acc[m][n], 0, 0, 0);
    }
  }

  int yo = y0 + wid;
  if (out_nhwc) {
#pragma unroll
    for (int m = 0; m < 4; ++m) {
      int cog = co_base + m * 16 + kg * 4;
      f32x4 d4 = *(const f32x4*)&dmod[b * C + cog];
      f32x4 n4 = *(const f32x4*)&nscale[cog];
      f32x4 s4 = *(const f32x4*)&s2v[b * C + cog];
#pragma unroll
      for (int n = 0; n < 4; ++n) {
        int xo = n * 16 + ln;
        float nz = noise[b * HW + yo * 64 + xo];
        f16x4 o;
#pragma unroll
        for (int r = 0; r < 4; ++r) {
          float v = fmaf(acc[m][n][r], d4[r], n4[r] * nz);
          v = v >= 0.f ? v : LRELU * v;
          o[r] = (f16)(v * s4[r]);
        }
        *(f16x4*)&out_nhwc[(((size_t)b * 64 + yo) * 64 + xo) * C + cog] = o;
      }
    }
  } else {
#pragma unroll
    for (int m = 0; m < 4; ++m) {
      int cog = co_base + m * 16 + kg * 4;
      f32x4 d4 = *(const f32x4*)&dmod[b * C + cog];
      f32x4 n4 = *(const f32x4*)&nscale[cog];
#pragma unroll
      for (int n = 0; n < 4; ++n) {
        int xo = n * 16 + ln;
        float nz = noise[b * HW + yo * 64 + xo];
#pragma unroll
        for (int r = 0; r < 4; ++r) {
          float v = fmaf(acc[m][n][r], d4[r], n4[r] * nz);
          v = v >= 0.f ? v : LRELU * v;
          out_nchw[(((size_t)b * C + cog + r) * 64 + yo) * 64 + xo] = v;
        }
      }
    }
  }
}

// ---------------------------------------------------------------------------
// 1x1 toRGB: rgb[b][c][p] = sum_co (rgbW[c][co] * sr[b][co]) * h[b][co][p]
__global__ void k_rgb(const float* __restrict__ h,    // [B][C][HW] fp32
                      const float* __restrict__ rw,   // [3][C]
                      const float* __restrict__ sr,   // [B][C]
                      float* __restrict__ rgb) {      // [B][3][HW]
  __shared__ float wsr[3][C];
  int bx = blockIdx.x;
  int b = bx >> 5;
  int chunk = bx & 31;
  int t = threadIdx.x;
  for (int idx = t; idx < 3 * C; idx += 128) {
    int c = idx >> 9, co = idx & 511;
    wsr[c][co] = rw[c * C + co] * sr[b * C + co];
  }
  __syncthreads();
  int px = chunk * 128 + t;
  float a0 = 0.f, a1 = 0.f, a2 = 0.f;
  const float* hp = h + (size_t)b * C * HW + px;
#pragma unroll 4
  for (int co = 0; co < C; ++co) {
    float hv = hp[(size_t)co * HW];
    a0 = fmaf(wsr[0][co], hv, a0);
    a1 = fmaf(wsr[1][co], hv, a1);
    a2 = fmaf(wsr[2][co], hv, a2);
  }
  float* rp = rgb + (size_t)b * 3 * HW + px;
  rp[0] = a0;
  rp[HW] = a1;
  rp[2 * HW] = a2;
}

// ---------------------------------------------------------------------------
extern "C" void kernel_launch(void* const* d_in, const int* in_sizes, int n_in,
                              void* d_out, int out_size, void* d_ws, size_t ws_size,
                              hipStream_t stream) {
  (void)in_sizes; (void)n_in; (void)out_size; (void)ws_size;
  const float* x   = (const float*)d_in[0];
  const float* wst = (const float*)d_in[1];
  const float* w1  = (const float*)d_in[2];
  const float* m1w = (const float*)d_in[3];
  const float* m1b = (const float*)d_in[4];
  const float* ns1 = (const float*)d_in[5];
  const float* w2  = (const float*)d_in[6];
  const float* m2w = (const float*)d_in[7];
  const float* m2b = (const float*)d_in[8];
  const float* ns2 = (const float*)d_in[9];
  const float* rw  = (const float*)d_in[10];
  const float* mrw = (const float*)d_in[11];
  const float* mrb = (const float*)d_in[12];
  const float* nz1 = (const float*)d_in[13];
  const float* nz2 = (const float*)d_in[14];

  char* wsb = (char*)d_ws;
  f16*   xup = (f16*)(wsb + XUP_B);
  f16*   h1s = (f16*)(wsb + H1S_B);
  f16*   wp1 = (f16*)(wsb + WP1_B);
  f16*   wp2 = (f16*)(wsb + WP2_B);
  float* s1  = (float*)(wsb + S1_B);
  float* s2  = (float*)(wsb + S2_B);
  float* srr = (float*)(wsb + SR_B);
  float* dm1 = (float*)(wsb + D1_B);
  float* dm2 = (float*)(wsb + D2_B);

  float* hout   = (float*)d_out;                  // [B][C][HW]
  float* rgbout = hout + (size_t)B * C * HW;      // [B][3][HW]

  k_styles<<<B, 256, 0, stream>>>(wst, m1w, m1b, s1);
  k_styles<<<B, 256, 0, stream>>>(wst, m2w, m2b, s2);
  k_styles<<<B, 256, 0, stream>>>(wst, mrw, mrb, srr);
  k_demod<<<C, 256, 0, stream>>>(w1, s1, dm1);
  k_demod<<<C, 256, 0, stream>>>(w2, s2, dm2);
  k_packw<<<C * C / 256, 256, 0, stream>>>(w1, wp1);
  k_packw<<<C * C / 256, 256, 0, stream>>>(w2, wp2);
  k_up<<<B * 16, 256, 0, stream>>>(x, s1, xup);
  k_conv_mfma<<<1024, 256, 0, stream>>>(xup, wp1, dm1, ns1, nz1, s2, h1s, nullptr);
  k_conv_mfma<<<1024, 256, 0, stream>>>(h1s, wp2, dm2, ns2, nz2, nullptr, nullptr, hout);
  k_rgb<<<B * 32, 128, 0, stream>>>(hout, rw, srr, rgbout);
}